// Round 1
// baseline (312.609 us; speedup 1.0000x reference)
//
#include <hip/hip_runtime.h>
#include <math.h>

#define HW 192
#define OW 182          // 192 - 11 + 1
#define NPIX (OW*OW)
#define SSIM_C1 0.01f   // (0.01*10)^2
#define SSIM_C2 0.09f   // (0.03*10)^2

__device__ __forceinline__ void dgauss(float g[11]) {
    float s = 0.f;
#pragma unroll
    for (int i = 0; i < 11; ++i) {
        float d = (float)(i - 5);
        g[i] = expf(-(d * d) / 4.5f);   // 2*sigma^2 = 4.5
        s += g[i];
    }
    float inv = 1.f / s;
#pragma unroll
    for (int i = 0; i < 11; ++i) g[i] *= inv;
}

// ---------------------------------------------------------------------------
// Kernel 1: mu_f, sig_f for the 24 feature images  (grid = 24*14, 256 thr)
// ---------------------------------------------------------------------------
__global__ __launch_bounds__(256) void muf_kernel(const float* __restrict__ xf,
                                                  float* __restrict__ muf,
                                                  float* __restrict__ sigf) {
    const int tile = blockIdx.x % 14;     // 14 tiles of 13 output rows
    const int img  = blockIdx.x / 14;     // b*3 + f
    const int r0   = tile * 13;

    __shared__ float raw[23][192];
    __shared__ float hb[2][23][184];

    float g[11]; dgauss(g);
    const int t = threadIdx.x;
    const float* src = xf + (size_t)img * HW * HW;

    for (int i = t; i < 23 * 192; i += 256) {
        int rr = i / 192, col = i - rr * 192;
        raw[rr][col] = src[(r0 + rr) * HW + col];
    }
    __syncthreads();

    for (int i = t; i < 23 * OW; i += 256) {
        int rr = i / OW, co = i - rr * OW;
        float a0 = 0.f, a1 = 0.f;
#pragma unroll
        for (int k = 0; k < 11; ++k) {
            float v = raw[rr][co + k];
            float w = g[k];
            a0 += w * v;
            a1 += w * v * v;
        }
        hb[0][rr][co] = a0;
        hb[1][rr][co] = a1;
    }
    __syncthreads();

    for (int i = t; i < 13 * OW; i += 256) {
        int rr = i / OW, co = i - rr * OW;
        float m = 0.f, s2 = 0.f;
#pragma unroll
        for (int k = 0; k < 11; ++k) {
            float w = g[k];
            m  += w * hb[0][rr + k][co];
            s2 += w * hb[1][rr + k][co];
        }
        size_t o = (size_t)img * NPIX + (size_t)(r0 + rr) * OW + co;
        muf[o]  = m;
        sigf[o] = s2 - m * m;
    }
}

// ---------------------------------------------------------------------------
// Kernel 2: fused SSIM for one (b,c) per block  (grid = 512, 256 thr)
// Streams rows; 12-row LDS ring of 5 h-blurred fields.
// ---------------------------------------------------------------------------
__global__ __launch_bounds__(256) void ssim_kernel(const float* __restrict__ x,
                                                   const float* __restrict__ xf,
                                                   const float* __restrict__ muf,
                                                   const float* __restrict__ sigf,
                                                   float* __restrict__ out_ssim) {
    const int bc = blockIdx.x;
    const int b  = bc >> 6;
    const int c  = bc & 63;

    const float* xp = x  + (size_t)(b * 64 + c) * HW * HW;
    const float* f0 = xf + (size_t)(b * 3 + 0) * HW * HW;
    const float* f1 = f0 + HW * HW;
    const float* f2 = f1 + HW * HW;
    const float* mu0 = muf  + (size_t)(b * 3 + 0) * NPIX;
    const float* mu1 = mu0 + NPIX;
    const float* mu2 = mu1 + NPIX;
    const float* sg0 = sigf + (size_t)(b * 3 + 0) * NPIX;
    const float* sg1 = sg0 + NPIX;
    const float* sg2 = sg1 + NPIX;

    __shared__ float rowx[192], rowf0[192], rowf1[192], rowf2[192];
    __shared__ float ring[5][12][184];
    __shared__ float red[3][4];

    float g[11]; dgauss(g);
    const int t = threadIdx.x;

    float acc0 = 0.f, acc1 = 0.f, acc2 = 0.f;

    for (int rin = 0; rin < HW; ++rin) {
        // ---- load raw row (coalesced, 192-wide) ----
        if (t < 192) {
            const int o = rin * HW + t;
            rowx [t] = xp[o];
            rowf0[t] = f0[o];
            rowf1[t] = f1[o];
            rowf2[t] = f2[o];
        }
        __syncthreads();

        // ---- horizontal blur of 5 fields into ring slot rin%12 ----
        const int sl = rin % 12;
        if (t < OW) {
            float a0 = 0.f, a1 = 0.f, a2 = 0.f, a3 = 0.f, a4 = 0.f;
#pragma unroll
            for (int k = 0; k < 11; ++k) {
                float w  = g[k];
                float xv = rowx[t + k];
                float wx = w * xv;
                a0 += wx;
                a1 += wx * xv;
                a2 += wx * rowf0[t + k];
                a3 += wx * rowf1[t + k];
                a4 += wx * rowf2[t + k];
            }
            ring[0][sl][t] = a0;
            ring[1][sl][t] = a1;
            ring[2][sl][t] = a2;
            ring[3][sl][t] = a3;
            ring[4][sl][t] = a4;
        }
        __syncthreads();

        // ---- vertical blur + SSIM for output row rin-10 ----
        if (rin >= 10 && t < OW) {
            const int rout = rin - 10;
            const int sbase = rout % 12;
            float mux = 0.f, sxx = 0.f, p0 = 0.f, p1 = 0.f, p2 = 0.f;
#pragma unroll
            for (int k = 0; k < 11; ++k) {
                int s = sbase + k; if (s >= 12) s -= 12;
                float w = g[k];
                mux += w * ring[0][s][t];
                sxx += w * ring[1][s][t];
                p0  += w * ring[2][s][t];
                p1  += w * ring[3][s][t];
                p2  += w * ring[4][s][t];
            }
            const float sigx = sxx - mux * mux;
            const int   po   = rout * OW + t;

            {
                float mf = mu0[po], sf = sg0[po];
                float sfx = p0 - mf * mux;
                float v1 = 2.f * sfx + SSIM_C2;
                float v2 = sf + sigx + SSIM_C2;
                float num = (2.f * mf * mux + SSIM_C1) * v1;
                float den = (mf * mf + mux * mux + SSIM_C1) * v2;
                acc0 += num / den;
            }
            {
                float mf = mu1[po], sf = sg1[po];
                float sfx = p1 - mf * mux;
                float v1 = 2.f * sfx + SSIM_C2;
                float v2 = sf + sigx + SSIM_C2;
                float num = (2.f * mf * mux + SSIM_C1) * v1;
                float den = (mf * mf + mux * mux + SSIM_C1) * v2;
                acc1 += num / den;
            }
            {
                float mf = mu2[po], sf = sg2[po];
                float sfx = p2 - mf * mux;
                float v1 = 2.f * sfx + SSIM_C2;
                float v2 = sf + sigx + SSIM_C2;
                float num = (2.f * mf * mux + SSIM_C1) * v1;
                float den = (mf * mf + mux * mux + SSIM_C1) * v2;
                acc2 += num / den;
            }
        }
    }

    // ---- reduction over block ----
#pragma unroll
    for (int off = 32; off > 0; off >>= 1) {
        acc0 += __shfl_down(acc0, off);
        acc1 += __shfl_down(acc1, off);
        acc2 += __shfl_down(acc2, off);
    }
    const int wid = t >> 6, lane = t & 63;
    if (lane == 0) { red[0][wid] = acc0; red[1][wid] = acc1; red[2][wid] = acc2; }
    __syncthreads();
    if (t == 0) {
        const float inv = 1.f / (float)NPIX;
        float s0 = (red[0][0] + red[0][1]) + (red[0][2] + red[0][3]);
        float s1 = (red[1][0] + red[1][1]) + (red[1][2] + red[1][3]);
        float s2 = (red[2][0] + red[2][1]) + (red[2][2] + red[2][3]);
        out_ssim[(b * 3 + 0) * 64 + c] = s0 * inv;
        out_ssim[(b * 3 + 1) * 64 + c] = s1 * inv;
        out_ssim[(b * 3 + 2) * 64 + c] = s2 * inv;
    }
}

// ---------------------------------------------------------------------------
// Kernel 3: spatial gate conv + MLP + sigmoid  (grid = 8, 64 thr)
// ---------------------------------------------------------------------------
__global__ __launch_bounds__(64) void gate_kernel(const float* __restrict__ ssim,
                                                  const float* __restrict__ sw,
                                                  const float* __restrict__ W1,
                                                  const float* __restrict__ b1,
                                                  const float* __restrict__ W2,
                                                  const float* __restrict__ b2,
                                                  float* __restrict__ out) {
    const int b = blockIdx.x;
    const int c = threadIdx.x;   // 0..63

    __shared__ float s[3][64];
    __shared__ float h0[64];
    __shared__ float h1[64];

#pragma unroll
    for (int f = 0; f < 3; ++f) s[f][c] = ssim[(b * 3 + f) * 64 + c];
    __syncthreads();

    float a = 0.f;
#pragma unroll
    for (int f = 0; f < 3; ++f)
#pragma unroll
        for (int i = 0; i < 3; ++i) {
            int cc = c - 1 + i;
            if (cc >= 0 && cc < 64) a += sw[f * 3 + i] * s[f][cc];
        }
    h0[c] = fmaxf(a, 0.f);
    __syncthreads();

    float a1 = b1[c];
    for (int j = 0; j < 64; ++j) a1 += W1[c * 64 + j] * h0[j];
    h1[c] = fmaxf(a1, 0.f);
    __syncthreads();

    float a2 = b2[c];
    for (int j = 0; j < 64; ++j) a2 += W2[c * 64 + j] * h1[j];
    out[b * 64 + c] = 1.f / (1.f + expf(-a2));
}

// ---------------------------------------------------------------------------
extern "C" void kernel_launch(void* const* d_in, const int* in_sizes, int n_in,
                              void* d_out, int out_size, void* d_ws, size_t ws_size,
                              hipStream_t stream) {
    const float* x  = (const float*)d_in[0];
    const float* xf = (const float*)d_in[1];
    const float* sw = (const float*)d_in[2];
    const float* W1 = (const float*)d_in[3];
    const float* b1 = (const float*)d_in[4];
    const float* W2 = (const float*)d_in[5];
    const float* b2 = (const float*)d_in[6];
    float* out = (float*)d_out;

    float* muf  = (float*)d_ws;            // [24][182][182]
    float* sigf = muf + 24 * NPIX;         // [24][182][182]

    muf_kernel <<<24 * 14, 256, 0, stream>>>(xf, muf, sigf);
    ssim_kernel<<<512,     256, 0, stream>>>(x, xf, muf, sigf, out + 512);
    gate_kernel<<<8,        64, 0, stream>>>(out + 512, sw, W1, b1, W2, b2, out);
}

// Round 2
// 148.646 us; speedup vs baseline: 2.1030x; 2.1030x over previous
//
#include <hip/hip_runtime.h>
#include <math.h>

#define HW 192
#define OW 182          // 192 - 11 + 1
#define NPIX (OW*OW)
#define SSIM_C1 0.01f   // (0.01*10)^2
#define SSIM_C2 0.09f   // (0.03*10)^2

// normalized gaussian, ws=11 sigma=1.5 (symmetric)
#define G0 0.0010283835f
#define G1 0.0075987615f
#define G2 0.0360007700f
#define G3 0.1093608000f
#define G4 0.2130055400f
#define G5 0.2660117000f

__device__ __forceinline__ void dgauss(float g[11]) {
    float s = 0.f;
#pragma unroll
    for (int i = 0; i < 11; ++i) {
        float d = (float)(i - 5);
        g[i] = expf(-(d * d) / 4.5f);
        s += g[i];
    }
    float inv = 1.f / s;
#pragma unroll
    for (int i = 0; i < 11; ++i) g[i] *= inv;
}

// ---------------------------------------------------------------------------
// Kernel 1: mu_f, sig_f for the 24 feature images  (grid = 24*14, 256 thr)
// ---------------------------------------------------------------------------
__global__ __launch_bounds__(256) void muf_kernel(const float* __restrict__ xf,
                                                  float* __restrict__ muf,
                                                  float* __restrict__ sigf) {
    const int tile = blockIdx.x % 14;
    const int img  = blockIdx.x / 14;
    const int r0   = tile * 13;

    __shared__ float raw[23][192];
    __shared__ float hb[2][23][184];

    float g[11]; dgauss(g);
    const int t = threadIdx.x;
    const float* src = xf + (size_t)img * HW * HW;

    for (int i = t; i < 23 * 192; i += 256) {
        int rr = i / 192, col = i - rr * 192;
        raw[rr][col] = src[(r0 + rr) * HW + col];
    }
    __syncthreads();

    for (int i = t; i < 23 * OW; i += 256) {
        int rr = i / OW, co = i - rr * OW;
        float a0 = 0.f, a1 = 0.f;
#pragma unroll
        for (int k = 0; k < 11; ++k) {
            float v = raw[rr][co + k];
            float w = g[k];
            a0 += w * v;
            a1 += w * v * v;
        }
        hb[0][rr][co] = a0;
        hb[1][rr][co] = a1;
    }
    __syncthreads();

    for (int i = t; i < 13 * OW; i += 256) {
        int rr = i / OW, co = i - rr * OW;
        float m = 0.f, s2 = 0.f;
#pragma unroll
        for (int k = 0; k < 11; ++k) {
            float w = g[k];
            m  += w * hb[0][rr + k][co];
            s2 += w * hb[1][rr + k][co];
        }
        size_t o = (size_t)img * NPIX + (size_t)(r0 + rr) * OW + co;
        muf[o]  = m;
        sigf[o] = s2 - m * m;
    }
}

// ---------------------------------------------------------------------------
// Kernel 2: fused SSIM. One (b,c,row-tile) per block; grid = 8*64*4 = 2048.
// Vertical blur in registers (pending accumulators), LDS only for the
// emitted h-blur row (double-buffered, 1 barrier/row).
// ---------------------------------------------------------------------------
__global__ __launch_bounds__(192, 4) void ssim_kernel(const float* __restrict__ x,
                                                      const float* __restrict__ xf,
                                                      const float* __restrict__ muf,
                                                      const float* __restrict__ sigf,
                                                      float* __restrict__ part) {
    constexpr float G[11] = {G0,G1,G2,G3,G4,G5,G4,G3,G2,G1,G0};

    const int blk  = blockIdx.x;
    const int c    = blk & 63;
    const int tile = (blk >> 6) & 3;
    const int b    = blk >> 8;

    const int out0  = (tile * 182) >> 2;        // 0,45,91,136
    const int out1  = ((tile + 1) * 182) >> 2;  // 45,91,136,182
    const int n_out = out1 - out0;
    const int n_in  = n_out + 10;

    const float* xp = x  + ((size_t)(b * 64 + c)) * HW * HW + (size_t)out0 * HW;
    const float* f0 = xf + ((size_t)(b * 3 + 0)) * HW * HW + (size_t)out0 * HW;
    const float* f1 = f0 + HW * HW;
    const float* f2 = f1 + HW * HW;
    const float* mu0 = muf  + (size_t)(b * 3) * NPIX;
    const float* mu1 = mu0 + NPIX;
    const float* mu2 = mu1 + NPIX;
    const float* sg0 = sigf + (size_t)(b * 3) * NPIX;
    const float* sg1 = sg0 + NPIX;
    const float* sg2 = sg1 + NPIX;

    __shared__ float vbuf[2][5][192];
    __shared__ float red[3][3];

    const int t = threadIdx.x;

    // pending vertical accumulators: P[f][j] = partial of output row (r-10+j)
    float P[5][10];
#pragma unroll
    for (int f = 0; f < 5; ++f)
#pragma unroll
        for (int j = 0; j < 10; ++j) P[f][j] = 0.f;

    float acc0 = 0.f, acc1 = 0.f, acc2 = 0.f;
    int buf = 0;

    for (int r = 0; r < n_in; ++r) {
        const int go = r * HW + t;
        const float xv = xp[go];
        const float a0 = f0[go];
        const float a1 = f1[go];
        const float a2 = f2[go];

        // prefetch SSIM per-pixel moments for the row we emit this iteration
        float mf0, sf0, mf1, sf1, mf2, sf2;
        const bool hb = (r >= 10) && (t < OW);
        if (hb) {
            const int po = (out0 + r - 10) * OW + t;
            mf0 = mu0[po]; sf0 = sg0[po];
            mf1 = mu1[po]; sf1 = sg1[po];
            mf2 = mu2[po]; sf2 = sg2[po];
        }

        const float v0 = xv;
        const float v1 = xv * xv;
        const float v2 = xv * a0;
        const float v3 = xv * a1;
        const float v4 = xv * a2;

        // emit values (vertical blur of output row r-10 completes with row r)
        const float e0 = fmaf(G[10], v0, P[0][0]);
        const float e1 = fmaf(G[10], v1, P[1][0]);
        const float e2 = fmaf(G[10], v2, P[2][0]);
        const float e3 = fmaf(G[10], v3, P[3][0]);
        const float e4 = fmaf(G[10], v4, P[4][0]);

        // fused shift+accumulate
#pragma unroll
        for (int j = 0; j < 9; ++j) {
            P[0][j] = fmaf(G[9 - j], v0, P[0][j + 1]);
            P[1][j] = fmaf(G[9 - j], v1, P[1][j + 1]);
            P[2][j] = fmaf(G[9 - j], v2, P[2][j + 1]);
            P[3][j] = fmaf(G[9 - j], v3, P[3][j + 1]);
            P[4][j] = fmaf(G[9 - j], v4, P[4][j + 1]);
        }
        P[0][9] = G[0] * v0;
        P[1][9] = G[0] * v1;
        P[2][9] = G[0] * v2;
        P[3][9] = G[0] * v3;
        P[4][9] = G[0] * v4;

        if (r >= 10) {
            vbuf[buf][0][t] = e0;
            vbuf[buf][1][t] = e1;
            vbuf[buf][2][t] = e2;
            vbuf[buf][3][t] = e3;
            vbuf[buf][4][t] = e4;
            __syncthreads();

            if (t < OW) {
                float mux = 0.f, sxx = 0.f, p0 = 0.f, p1 = 0.f, p2 = 0.f;
#pragma unroll
                for (int k = 0; k < 11; ++k) {
                    const float w = G[k];
                    mux = fmaf(w, vbuf[buf][0][t + k], mux);
                    sxx = fmaf(w, vbuf[buf][1][t + k], sxx);
                    p0  = fmaf(w, vbuf[buf][2][t + k], p0);
                    p1  = fmaf(w, vbuf[buf][3][t + k], p1);
                    p2  = fmaf(w, vbuf[buf][4][t + k], p2);
                }
                const float sigx = sxx - mux * mux;
                const float mux2 = mux * mux;
                {
                    const float sfx = p0 - mf0 * mux;
                    const float v1s = 2.f * sfx + SSIM_C2;
                    const float v2s = sf0 + sigx + SSIM_C2;
                    const float num = (2.f * mf0 * mux + SSIM_C1) * v1s;
                    const float den = (mf0 * mf0 + mux2 + SSIM_C1) * v2s;
                    acc0 += num * __builtin_amdgcn_rcpf(den) ;
                }
                {
                    const float sfx = p1 - mf1 * mux;
                    const float v1s = 2.f * sfx + SSIM_C2;
                    const float v2s = sf1 + sigx + SSIM_C2;
                    const float num = (2.f * mf1 * mux + SSIM_C1) * v1s;
                    const float den = (mf1 * mf1 + mux2 + SSIM_C1) * v2s;
                    acc1 += num * __builtin_amdgcn_rcpf(den);
                }
                {
                    const float sfx = p2 - mf2 * mux;
                    const float v1s = 2.f * sfx + SSIM_C2;
                    const float v2s = sf2 + sigx + SSIM_C2;
                    const float num = (2.f * mf2 * mux + SSIM_C1) * v1s;
                    const float den = (mf2 * mf2 + mux2 + SSIM_C1) * v2s;
                    acc2 += num * __builtin_amdgcn_rcpf(den);
                }
            }
            buf ^= 1;
        }
    }

    // block reduction (3 waves)
#pragma unroll
    for (int off = 32; off > 0; off >>= 1) {
        acc0 += __shfl_down(acc0, off);
        acc1 += __shfl_down(acc1, off);
        acc2 += __shfl_down(acc2, off);
    }
    const int wid = t >> 6, lane = t & 63;
    if (lane == 0) { red[0][wid] = acc0; red[1][wid] = acc1; red[2][wid] = acc2; }
    __syncthreads();
    if (t == 0) {
        const size_t o = (size_t)tile * 1536 + (size_t)b * 192;
        part[o +   0 + c] = red[0][0] + red[0][1] + red[0][2];
        part[o +  64 + c] = red[1][0] + red[1][1] + red[1][2];
        part[o + 128 + c] = red[2][0] + red[2][1] + red[2][2];
    }
}

// ---------------------------------------------------------------------------
// Kernel 3: combine tile partials -> ssim_info, then conv gate + MLP + sigmoid
// grid = 8, 64 thr
// ---------------------------------------------------------------------------
__global__ __launch_bounds__(64) void gate_kernel(const float* __restrict__ part,
                                                  const float* __restrict__ sw,
                                                  const float* __restrict__ W1,
                                                  const float* __restrict__ b1,
                                                  const float* __restrict__ W2,
                                                  const float* __restrict__ b2,
                                                  float* __restrict__ out,
                                                  float* __restrict__ out_ssim) {
    const int b = blockIdx.x;
    const int c = threadIdx.x;   // 0..63

    __shared__ float s[3][64];
    __shared__ float h0[64];
    __shared__ float h1[64];

    const float inv = 1.f / (float)NPIX;
#pragma unroll
    for (int f = 0; f < 3; ++f) {
        const int i = b * 192 + f * 64 + c;
        float v = (part[i] + part[1536 + i]) + (part[3072 + i] + part[4608 + i]);
        v *= inv;
        s[f][c] = v;
        out_ssim[i] = v;
    }
    __syncthreads();

    float a = 0.f;
#pragma unroll
    for (int f = 0; f < 3; ++f)
#pragma unroll
        for (int i = 0; i < 3; ++i) {
            int cc = c - 1 + i;
            if (cc >= 0 && cc < 64) a += sw[f * 3 + i] * s[f][cc];
        }
    h0[c] = fmaxf(a, 0.f);
    __syncthreads();

    float a1 = b1[c];
    for (int j = 0; j < 64; ++j) a1 += W1[c * 64 + j] * h0[j];
    h1[c] = fmaxf(a1, 0.f);
    __syncthreads();

    float a2 = b2[c];
    for (int j = 0; j < 64; ++j) a2 += W2[c * 64 + j] * h1[j];
    out[b * 64 + c] = 1.f / (1.f + expf(-a2));
}

// ---------------------------------------------------------------------------
extern "C" void kernel_launch(void* const* d_in, const int* in_sizes, int n_in,
                              void* d_out, int out_size, void* d_ws, size_t ws_size,
                              hipStream_t stream) {
    const float* x  = (const float*)d_in[0];
    const float* xf = (const float*)d_in[1];
    const float* sw = (const float*)d_in[2];
    const float* W1 = (const float*)d_in[3];
    const float* b1 = (const float*)d_in[4];
    const float* W2 = (const float*)d_in[5];
    const float* b2 = (const float*)d_in[6];
    float* out = (float*)d_out;

    float* muf  = (float*)d_ws;            // [24][182*182]
    float* sigf = muf + 24 * NPIX;         // [24][182*182]
    float* part = sigf + 24 * NPIX;        // [4][8][3][64]

    muf_kernel <<<24 * 14, 256, 0, stream>>>(xf, muf, sigf);
    ssim_kernel<<<2048,    192, 0, stream>>>(x, xf, muf, sigf, part);
    gate_kernel<<<8,        64, 0, stream>>>(part, sw, W1, b1, W2, b2, out, out + 512);
}

// Round 3
// 112.073 us; speedup vs baseline: 2.7893x; 1.3263x over previous
//
#include <hip/hip_runtime.h>
#include <math.h>

#define HW 192
#define OW 182          // 192 - 11 + 1
#define NPIX (OW*OW)
#define SSIM_C1 0.01f   // (0.01*10)^2
#define SSIM_C2 0.09f   // (0.03*10)^2

// normalized gaussian, ws=11 sigma=1.5 (symmetric)
#define Gk0 0.0010283835f
#define Gk1 0.0075987615f
#define Gk2 0.0360007700f
#define Gk3 0.1093608000f
#define Gk4 0.2130055400f
#define Gk5 0.2660117000f

typedef float v2f __attribute__((ext_vector_type(2)));

__device__ __forceinline__ v2f vfma(float w, v2f a, v2f b) {
    return __builtin_elementwise_fma((v2f){w, w}, a, b);
}
__device__ __forceinline__ v2f vfma2(v2f w, v2f a, v2f b) {
    return __builtin_elementwise_fma(w, a, b);
}

__device__ __forceinline__ void dgauss(float g[11]) {
    float s = 0.f;
#pragma unroll
    for (int i = 0; i < 11; ++i) {
        float d = (float)(i - 5);
        g[i] = expf(-(d * d) / 4.5f);
        s += g[i];
    }
    float inv = 1.f / s;
#pragma unroll
    for (int i = 0; i < 11; ++i) g[i] *= inv;
}

// ---------------------------------------------------------------------------
// Kernel 1: mu_f and (sig_f + C2) for the 24 feature images (grid=24*14, 256t)
// ---------------------------------------------------------------------------
__global__ __launch_bounds__(256) void muf_kernel(const float* __restrict__ xf,
                                                  float* __restrict__ muf,
                                                  float* __restrict__ sigc2f) {
    const int tile = blockIdx.x % 14;
    const int img  = blockIdx.x / 14;
    const int r0   = tile * 13;

    __shared__ float raw[23][192];
    __shared__ float hb[2][23][184];

    float g[11]; dgauss(g);
    const int t = threadIdx.x;
    const float* src = xf + (size_t)img * HW * HW;

    for (int i = t; i < 23 * 192; i += 256) {
        int rr = i / 192, col = i - rr * 192;
        raw[rr][col] = src[(r0 + rr) * HW + col];
    }
    __syncthreads();

    for (int i = t; i < 23 * OW; i += 256) {
        int rr = i / OW, co = i - rr * OW;
        float a0 = 0.f, a1 = 0.f;
#pragma unroll
        for (int k = 0; k < 11; ++k) {
            float v = raw[rr][co + k];
            float w = g[k];
            a0 += w * v;
            a1 += w * v * v;
        }
        hb[0][rr][co] = a0;
        hb[1][rr][co] = a1;
    }
    __syncthreads();

    for (int i = t; i < 13 * OW; i += 256) {
        int rr = i / OW, co = i - rr * OW;
        float m = 0.f, s2 = 0.f;
#pragma unroll
        for (int k = 0; k < 11; ++k) {
            float w = g[k];
            m  += w * hb[0][rr + k][co];
            s2 += w * hb[1][rr + k][co];
        }
        size_t o = (size_t)img * NPIX + (size_t)(r0 + rr) * OW + co;
        muf[o]    = m;
        sigc2f[o] = s2 - m * m + SSIM_C2;
    }
}

// ---------------------------------------------------------------------------
// Kernel 2: fused SSIM. One (b,c,row-tile) per block; grid = 2048, 192 thr.
// Vertical blur in registers (packed pending accumulators). 2 rows / iter,
// 1 barrier / iter. Horizontal: 2 cols per thread via stride-2 b64 LDS reads,
// threads 0..95 -> row A, 96..191 -> row B. Packed f32 throughout.
// ---------------------------------------------------------------------------
__global__ __launch_bounds__(192, 4) void ssim_kernel(const float* __restrict__ x,
                                                      const float* __restrict__ xf,
                                                      const float* __restrict__ muf,
                                                      const float* __restrict__ sigc2f,
                                                      float* __restrict__ part) {
    const float G[11] = {Gk0,Gk1,Gk2,Gk3,Gk4,Gk5,Gk4,Gk3,Gk2,Gk1,Gk0};
    const v2f WA[6] = {{G[0],0.f},{G[2],G[1]},{G[4],G[3]},{G[6],G[5]},{G[8],G[7]},{G[10],G[9]}};
    const v2f WB[6] = {{G[1],G[0]},{G[3],G[2]},{G[5],G[4]},{G[7],G[6]},{G[9],G[8]},{0.f,G[10]}};

    const int blk  = blockIdx.x;
    const int c    = blk & 63;
    const int tile = (blk >> 6) & 3;
    const int b    = blk >> 8;

    const int out0  = (tile * 182) >> 2;        // 0,45,91,136
    const int out1  = ((tile + 1) * 182) >> 2;  // 45,91,136,182
    const int n_out = out1 - out0;              // 45,46,45,46

    const int t    = threadIdx.x;
    const int half = (t >= 96) ? 1 : 0;
    const int u    = half ? (t - 96) : t;
    const int cu   = 2 * u;
    const bool act = (u <= 90);

    const float* xp  = x  + ((size_t)(b * 64 + c)) * HW * HW + (size_t)out0 * HW + t;
    const float* fp0 = xf + ((size_t)(b * 3 + 0)) * HW * HW + (size_t)out0 * HW + t;
    const float* fp1 = fp0 + HW * HW;
    const float* fp2 = fp1 + HW * HW;

    const float* mp = muf    + (size_t)(b * 3) * NPIX + (size_t)(out0 + half) * OW + cu;
    const float* cp = sigc2f + (size_t)(b * 3) * NPIX + (size_t)(out0 + half) * OW + cu;

    __shared__ float eb[4][5][192];
    __shared__ float red[3][3];

    // packed pending vertical accumulators
    v2f P01[10], P23[10];
    float P4[10];
#pragma unroll
    for (int j = 0; j < 10; ++j) { P01[j] = (v2f){0.f,0.f}; P23[j] = (v2f){0.f,0.f}; P4[j] = 0.f; }

    v2f A0 = {0.f,0.f}, A1 = {0.f,0.f}, A2 = {0.f,0.f};

    v2f eE01, eE23; float eE4;   // emit temps

    auto vstep = [&](float xv, float a0, float a1, float a2, bool emit) {
        v2f v01 = {xv, xv * xv};
        v2f v23 = {xv * a0, xv * a1};
        float v4 = xv * a2;
        if (emit) {
            eE01 = vfma(G[10], v01, P01[0]);
            eE23 = vfma(G[10], v23, P23[0]);
            eE4  = fmaf(G[10], v4, P4[0]);
        }
#pragma unroll
        for (int j = 0; j < 9; ++j) {
            P01[j] = vfma(G[9 - j], v01, P01[j + 1]);
            P23[j] = vfma(G[9 - j], v23, P23[j + 1]);
            P4[j]  = fmaf(G[9 - j], v4, P4[j + 1]);
        }
        P01[9] = G[0] * v01;
        P23[9] = G[0] * v23;
        P4[9]  = G[0] * v4;
    };

    // ---- prologue: rows 0..9, no emission, no LDS ----
#pragma unroll 1
    for (int r = 0; r < 10; r += 2) {
        float xA = xp[0],  aA0 = fp0[0],  aA1 = fp1[0],  aA2 = fp2[0];
        float xB = xp[HW], aB0 = fp0[HW], aB1 = fp1[HW], aB2 = fp2[HW];
        xp += 2 * HW; fp0 += 2 * HW; fp1 += 2 * HW; fp2 += 2 * HW;
        vstep(xA, aA0, aA1, aA2, false);
        vstep(xB, aB0, aB1, aB2, false);
    }

    const int n_pair = n_out >> 1;   // 22 or 23
    // ---- main loop: 2 emit rows per iteration ----
#pragma unroll 1
    for (int p = 0; p < n_pair; ++p) {
        const int e = 2 * p;                 // output rows e, e+1
        float xA = xp[0],  aA0 = fp0[0],  aA1 = fp1[0],  aA2 = fp2[0];
        float xB = xp[HW], aB0 = fp0[HW], aB1 = fp1[HW], aB2 = fp2[HW];
        xp += 2 * HW; fp0 += 2 * HW; fp1 += 2 * HW; fp2 += 2 * HW;

        v2f mf0, mf1, mf2, cc0, cc1, cc2;
        if (act) {   // moments for this thread's h-row (row e+half)
            mf0 = *(const v2f*)(mp);
            mf1 = *(const v2f*)(mp + NPIX);
            mf2 = *(const v2f*)(mp + 2 * NPIX);
            cc0 = *(const v2f*)(cp);
            cc1 = *(const v2f*)(cp + NPIX);
            cc2 = *(const v2f*)(cp + 2 * NPIX);
            mp += 2 * OW; cp += 2 * OW;
        }

        const int sA = e & 3, sB = (e + 1) & 3;
        vstep(xA, aA0, aA1, aA2, true);
        eb[sA][0][t] = eE01.x; eb[sA][1][t] = eE01.y;
        eb[sA][2][t] = eE23.x; eb[sA][3][t] = eE23.y;
        eb[sA][4][t] = eE4;
        vstep(xB, aB0, aB1, aB2, true);
        eb[sB][0][t] = eE01.x; eb[sB][1][t] = eE01.y;
        eb[sB][2][t] = eE23.x; eb[sB][3][t] = eE23.y;
        eb[sB][4][t] = eE4;
        __syncthreads();

        if (act) {
            const int sH = half ? sB : sA;
            v2f h0, h1, h2, h3, h4;
            {
                v2f hacc[5];
#pragma unroll
                for (int f = 0; f < 5; ++f) {
                    const float* ep = &eb[sH][f][cu];
                    v2f a = {0.f, 0.f};
#pragma unroll
                    for (int m = 0; m < 6; ++m) {
                        v2f rd = *(const v2f*)(ep + 2 * m);
                        a = vfma2(WA[m], __builtin_shufflevector(rd, rd, 0, 0), a);
                        a = vfma2(WB[m], __builtin_shufflevector(rd, rd, 1, 1), a);
                    }
                    hacc[f] = a;
                }
                h0 = hacc[0]; h1 = hacc[1]; h2 = hacc[2]; h3 = hacc[3]; h4 = hacc[4];
            }
            const v2f mux  = h0;
            const v2f mux2 = mux * mux;
            const v2f sigc = h1 - mux2;           // sxx - mux^2
            {
                v2f t1  = mf0 * mux;
                v2f sfx = h2 - t1;
                v2f v1s = vfma(2.f, sfx, (v2f){SSIM_C2, SSIM_C2});
                v2f n1  = vfma(2.f, t1, (v2f){SSIM_C1, SSIM_C1});
                v2f num = n1 * v1s;
                v2f qd  = vfma2(mf0, mf0, (v2f){SSIM_C1, SSIM_C1});
                v2f den = (qd + mux2) * (cc0 + sigc);
                v2f inv = {__builtin_amdgcn_rcpf(den.x), __builtin_amdgcn_rcpf(den.y)};
                A0 = vfma2(num, inv, A0);
            }
            {
                v2f t1  = mf1 * mux;
                v2f sfx = h3 - t1;
                v2f v1s = vfma(2.f, sfx, (v2f){SSIM_C2, SSIM_C2});
                v2f n1  = vfma(2.f, t1, (v2f){SSIM_C1, SSIM_C1});
                v2f num = n1 * v1s;
                v2f qd  = vfma2(mf1, mf1, (v2f){SSIM_C1, SSIM_C1});
                v2f den = (qd + mux2) * (cc1 + sigc);
                v2f inv = {__builtin_amdgcn_rcpf(den.x), __builtin_amdgcn_rcpf(den.y)};
                A1 = vfma2(num, inv, A1);
            }
            {
                v2f t1  = mf2 * mux;
                v2f sfx = h4 - t1;
                v2f v1s = vfma(2.f, sfx, (v2f){SSIM_C2, SSIM_C2});
                v2f n1  = vfma(2.f, t1, (v2f){SSIM_C1, SSIM_C1});
                v2f num = n1 * v1s;
                v2f qd  = vfma2(mf2, mf2, (v2f){SSIM_C1, SSIM_C1});
                v2f den = (qd + mux2) * (cc2 + sigc);
                v2f inv = {__builtin_amdgcn_rcpf(den.x), __builtin_amdgcn_rcpf(den.y)};
                A2 = vfma2(num, inv, A2);
            }
        }
    }

    // ---- odd tail row (n_out = 45 tiles) ----
    if (n_out & 1) {
        const int e = n_out - 1;
        float xA = xp[0], aA0 = fp0[0], aA1 = fp1[0], aA2 = fp2[0];
        vstep(xA, aA0, aA1, aA2, true);
        const int sA = e & 3;
        eb[sA][0][t] = eE01.x; eb[sA][1][t] = eE01.y;
        eb[sA][2][t] = eE23.x; eb[sA][3][t] = eE23.y;
        eb[sA][4][t] = eE4;
        __syncthreads();
        if (act && half == 0) {
            v2f mf0 = *(const v2f*)(mp);
            v2f mf1 = *(const v2f*)(mp + NPIX);
            v2f mf2 = *(const v2f*)(mp + 2 * NPIX);
            v2f cc0 = *(const v2f*)(cp);
            v2f cc1 = *(const v2f*)(cp + NPIX);
            v2f cc2 = *(const v2f*)(cp + 2 * NPIX);
            v2f hacc[5];
#pragma unroll
            for (int f = 0; f < 5; ++f) {
                const float* ep = &eb[sA][f][cu];
                v2f a = {0.f, 0.f};
#pragma unroll
                for (int m = 0; m < 6; ++m) {
                    v2f rd = *(const v2f*)(ep + 2 * m);
                    a = vfma2(WA[m], __builtin_shufflevector(rd, rd, 0, 0), a);
                    a = vfma2(WB[m], __builtin_shufflevector(rd, rd, 1, 1), a);
                }
                hacc[f] = a;
            }
            const v2f mux  = hacc[0];
            const v2f mux2 = mux * mux;
            const v2f sigc = hacc[1] - mux2;
            {
                v2f t1  = mf0 * mux;
                v2f sfx = hacc[2] - t1;
                v2f v1s = vfma(2.f, sfx, (v2f){SSIM_C2, SSIM_C2});
                v2f n1  = vfma(2.f, t1, (v2f){SSIM_C1, SSIM_C1});
                v2f num = n1 * v1s;
                v2f qd  = vfma2(mf0, mf0, (v2f){SSIM_C1, SSIM_C1});
                v2f den = (qd + mux2) * (cc0 + sigc);
                v2f inv = {__builtin_amdgcn_rcpf(den.x), __builtin_amdgcn_rcpf(den.y)};
                A0 = vfma2(num, inv, A0);
            }
            {
                v2f t1  = mf1 * mux;
                v2f sfx = hacc[3] - t1;
                v2f v1s = vfma(2.f, sfx, (v2f){SSIM_C2, SSIM_C2});
                v2f n1  = vfma(2.f, t1, (v2f){SSIM_C1, SSIM_C1});
                v2f num = n1 * v1s;
                v2f qd  = vfma2(mf1, mf1, (v2f){SSIM_C1, SSIM_C1});
                v2f den = (qd + mux2) * (cc1 + sigc);
                v2f inv = {__builtin_amdgcn_rcpf(den.x), __builtin_amdgcn_rcpf(den.y)};
                A1 = vfma2(num, inv, A1);
            }
            {
                v2f t1  = mf2 * mux;
                v2f sfx = hacc[4] - t1;
                v2f v1s = vfma(2.f, sfx, (v2f){SSIM_C2, SSIM_C2});
                v2f n1  = vfma(2.f, t1, (v2f){SSIM_C1, SSIM_C1});
                v2f num = n1 * v1s;
                v2f qd  = vfma2(mf2, mf2, (v2f){SSIM_C1, SSIM_C1});
                v2f den = (qd + mux2) * (cc2 + sigc);
                v2f inv = {__builtin_amdgcn_rcpf(den.x), __builtin_amdgcn_rcpf(den.y)};
                A2 = vfma2(num, inv, A2);
            }
        }
    }

    // ---- block reduction (3 waves) ----
    float acc0 = A0.x + A0.y;
    float acc1 = A1.x + A1.y;
    float acc2 = A2.x + A2.y;
#pragma unroll
    for (int off = 32; off > 0; off >>= 1) {
        acc0 += __shfl_down(acc0, off);
        acc1 += __shfl_down(acc1, off);
        acc2 += __shfl_down(acc2, off);
    }
    const int wid = t >> 6, lane = t & 63;
    if (lane == 0) { red[0][wid] = acc0; red[1][wid] = acc1; red[2][wid] = acc2; }
    __syncthreads();
    if (t == 0) {
        const size_t o = (size_t)tile * 1536 + (size_t)b * 192;
        part[o +   0 + c] = red[0][0] + red[0][1] + red[0][2];
        part[o +  64 + c] = red[1][0] + red[1][1] + red[1][2];
        part[o + 128 + c] = red[2][0] + red[2][1] + red[2][2];
    }
}

// ---------------------------------------------------------------------------
// Kernel 3: combine tile partials -> ssim_info, then conv gate + MLP + sigmoid
// ---------------------------------------------------------------------------
__global__ __launch_bounds__(64) void gate_kernel(const float* __restrict__ part,
                                                  const float* __restrict__ sw,
                                                  const float* __restrict__ W1,
                                                  const float* __restrict__ b1,
                                                  const float* __restrict__ W2,
                                                  const float* __restrict__ b2,
                                                  float* __restrict__ out,
                                                  float* __restrict__ out_ssim) {
    const int b = blockIdx.x;
    const int c = threadIdx.x;   // 0..63

    __shared__ float s[3][64];
    __shared__ float h0[64];
    __shared__ float h1[64];

    const float inv = 1.f / (float)NPIX;
#pragma unroll
    for (int f = 0; f < 3; ++f) {
        const int i = b * 192 + f * 64 + c;
        float v = (part[i] + part[1536 + i]) + (part[3072 + i] + part[4608 + i]);
        v *= inv;
        s[f][c] = v;
        out_ssim[i] = v;
    }
    __syncthreads();

    float a = 0.f;
#pragma unroll
    for (int f = 0; f < 3; ++f)
#pragma unroll
        for (int i = 0; i < 3; ++i) {
            int cc = c - 1 + i;
            if (cc >= 0 && cc < 64) a += sw[f * 3 + i] * s[f][cc];
        }
    h0[c] = fmaxf(a, 0.f);
    __syncthreads();

    float a1 = b1[c];
    for (int j = 0; j < 64; ++j) a1 += W1[c * 64 + j] * h0[j];
    h1[c] = fmaxf(a1, 0.f);
    __syncthreads();

    float a2 = b2[c];
    for (int j = 0; j < 64; ++j) a2 += W2[c * 64 + j] * h1[j];
    out[b * 64 + c] = 1.f / (1.f + expf(-a2));
}

// ---------------------------------------------------------------------------
extern "C" void kernel_launch(void* const* d_in, const int* in_sizes, int n_in,
                              void* d_out, int out_size, void* d_ws, size_t ws_size,
                              hipStream_t stream) {
    const float* x  = (const float*)d_in[0];
    const float* xf = (const float*)d_in[1];
    const float* sw = (const float*)d_in[2];
    const float* W1 = (const float*)d_in[3];
    const float* b1 = (const float*)d_in[4];
    const float* W2 = (const float*)d_in[5];
    const float* b2 = (const float*)d_in[6];
    float* out = (float*)d_out;

    float* muf  = (float*)d_ws;            // [24][182*182]
    float* sigf = muf + 24 * NPIX;         // [24][182*182]  (sig + C2)
    float* part = sigf + 24 * NPIX;        // [4][8][3][64]

    muf_kernel <<<24 * 14, 256, 0, stream>>>(xf, muf, sigf);
    ssim_kernel<<<2048,    192, 0, stream>>>(x, xf, muf, sigf, part);
    gate_kernel<<<8,        64, 0, stream>>>(part, sw, W1, b1, W2, b2, out, out + 512);
}

// Round 4
// 108.540 us; speedup vs baseline: 2.8801x; 1.0325x over previous
//
#include <hip/hip_runtime.h>
#include <math.h>

#define HW 192
#define OW 182          // 192 - 11 + 1
#define NPIX (OW*OW)
#define NTILE 8
#define SSIM_C1 0.01f   // (0.01*10)^2
#define SSIM_C2 0.09f   // (0.03*10)^2

// normalized gaussian, ws=11 sigma=1.5 (symmetric)
#define Gk0 0.0010283835f
#define Gk1 0.0075987615f
#define Gk2 0.0360007700f
#define Gk3 0.1093608000f
#define Gk4 0.2130055400f
#define Gk5 0.2660117000f

typedef float v2f __attribute__((ext_vector_type(2)));

__device__ __forceinline__ v2f vfma(float w, v2f a, v2f b) {
    return __builtin_elementwise_fma((v2f){w, w}, a, b);
}
__device__ __forceinline__ v2f vfma2(v2f w, v2f a, v2f b) {
    return __builtin_elementwise_fma(w, a, b);
}

__device__ __forceinline__ void dgauss(float g[11]) {
    float s = 0.f;
#pragma unroll
    for (int i = 0; i < 11; ++i) {
        float d = (float)(i - 5);
        g[i] = expf(-(d * d) / 4.5f);
        s += g[i];
    }
    float inv = 1.f / s;
#pragma unroll
    for (int i = 0; i < 11; ++i) g[i] *= inv;
}

// ---------------------------------------------------------------------------
// Kernel 1: mu_f and (sig_f + C2) for the 24 feature images (grid=24*14, 256t)
// ---------------------------------------------------------------------------
__global__ __launch_bounds__(256) void muf_kernel(const float* __restrict__ xf,
                                                  float* __restrict__ muf,
                                                  float* __restrict__ sigc2f) {
    const int tile = blockIdx.x % 14;
    const int img  = blockIdx.x / 14;
    const int r0   = tile * 13;

    __shared__ float raw[23][192];
    __shared__ float hb[2][23][184];

    float g[11]; dgauss(g);
    const int t = threadIdx.x;
    const float* src = xf + (size_t)img * HW * HW;

    for (int i = t; i < 23 * 192; i += 256) {
        int rr = i / 192, col = i - rr * 192;
        raw[rr][col] = src[(r0 + rr) * HW + col];
    }
    __syncthreads();

    for (int i = t; i < 23 * OW; i += 256) {
        int rr = i / OW, co = i - rr * OW;
        float a0 = 0.f, a1 = 0.f;
#pragma unroll
        for (int k = 0; k < 11; ++k) {
            float v = raw[rr][co + k];
            float w = g[k];
            a0 += w * v;
            a1 += w * v * v;
        }
        hb[0][rr][co] = a0;
        hb[1][rr][co] = a1;
    }
    __syncthreads();

    for (int i = t; i < 13 * OW; i += 256) {
        int rr = i / OW, co = i - rr * OW;
        float m = 0.f, s2 = 0.f;
#pragma unroll
        for (int k = 0; k < 11; ++k) {
            float w = g[k];
            m  += w * hb[0][rr + k][co];
            s2 += w * hb[1][rr + k][co];
        }
        size_t o = (size_t)img * NPIX + (size_t)(r0 + rr) * OW + co;
        muf[o]    = m;
        sigc2f[o] = s2 - m * m + SSIM_C2;
    }
}

// ---------------------------------------------------------------------------
// Kernel 2: fused SSIM. One (b,c,row-tile) per block; grid = 8*64*8 = 4096.
// Vertical blur in registers (packed pending accumulators). 2 rows / iter,
// 1 barrier / iter, stream loads software-pipelined one pair ahead.
// Horizontal: 2 cols per thread via stride-2 b64 LDS reads,
// threads 0..95 -> row A, 96..191 -> row B. Packed f32 throughout.
// ---------------------------------------------------------------------------
__global__ __launch_bounds__(192, 4) void ssim_kernel(const float* __restrict__ x,
                                                      const float* __restrict__ xf,
                                                      const float* __restrict__ muf,
                                                      const float* __restrict__ sigc2f,
                                                      float* __restrict__ part) {
    const float G[11] = {Gk0,Gk1,Gk2,Gk3,Gk4,Gk5,Gk4,Gk3,Gk2,Gk1,Gk0};
    const v2f WA[6] = {{G[0],0.f},{G[2],G[1]},{G[4],G[3]},{G[6],G[5]},{G[8],G[7]},{G[10],G[9]}};
    const v2f WB[6] = {{G[1],G[0]},{G[3],G[2]},{G[5],G[4]},{G[7],G[6]},{G[9],G[8]},{0.f,G[10]}};

    const int blk  = blockIdx.x;
    const int c    = blk & 63;
    const int tile = (blk >> 6) & 7;
    const int b    = blk >> 9;

    const int out0  = (tile * 182) >> 3;        // 0,22,45,68,91,113,136,159
    const int out1  = ((tile + 1) * 182) >> 3;  // 22,45,68,91,113,136,159,182
    const int n_out = out1 - out0;              // 22 or 23

    const int t    = threadIdx.x;
    const int half = (t >= 96) ? 1 : 0;
    const int u    = half ? (t - 96) : t;
    const int cu   = 2 * u;
    const bool act = (u <= 90);

    const float* xp  = x  + ((size_t)(b * 64 + c)) * HW * HW + (size_t)out0 * HW + t;
    const float* fp0 = xf + ((size_t)(b * 3 + 0)) * HW * HW + (size_t)out0 * HW + t;
    const float* fp1 = fp0 + HW * HW;
    const float* fp2 = fp1 + HW * HW;

    const float* mp = muf    + (size_t)(b * 3) * NPIX + (size_t)(out0 + half) * OW + cu;
    const float* cp = sigc2f + (size_t)(b * 3) * NPIX + (size_t)(out0 + half) * OW + cu;

    __shared__ float eb[4][5][192];
    __shared__ float red[3][3];

    // packed pending vertical accumulators
    v2f P01[10], P23[10];
    float P4[10];
#pragma unroll
    for (int j = 0; j < 10; ++j) { P01[j] = (v2f){0.f,0.f}; P23[j] = (v2f){0.f,0.f}; P4[j] = 0.f; }

    v2f A0 = {0.f,0.f}, A1 = {0.f,0.f}, A2 = {0.f,0.f};

    v2f eE01, eE23; float eE4;   // emit temps

    auto vstep = [&](float xv, float a0, float a1, float a2, bool emit) {
        v2f v01 = {xv, xv * xv};
        v2f v23 = {xv * a0, xv * a1};
        float v4 = xv * a2;
        if (emit) {
            eE01 = vfma(G[10], v01, P01[0]);
            eE23 = vfma(G[10], v23, P23[0]);
            eE4  = fmaf(G[10], v4, P4[0]);
        }
#pragma unroll
        for (int j = 0; j < 9; ++j) {
            P01[j] = vfma(G[9 - j], v01, P01[j + 1]);
            P23[j] = vfma(G[9 - j], v23, P23[j + 1]);
            P4[j]  = fmaf(G[9 - j], v4, P4[j + 1]);
        }
        P01[9] = G[0] * v01;
        P23[9] = G[0] * v23;
        P4[9]  = G[0] * v4;
    };

    auto ssim2 = [&](const v2f mux, const v2f sigc,
                     const v2f mf, const v2f cc, const v2f h, v2f& A) {
        const v2f mux2 = mux * mux;
        v2f t1  = mf * mux;
        v2f sfx = h - t1;
        v2f v1s = vfma(2.f, sfx, (v2f){SSIM_C2, SSIM_C2});
        v2f n1  = vfma(2.f, t1, (v2f){SSIM_C1, SSIM_C1});
        v2f num = n1 * v1s;
        v2f qd  = vfma2(mf, mf, (v2f){SSIM_C1, SSIM_C1});
        v2f den = (qd + mux2) * (cc + sigc);
        v2f inv = {__builtin_amdgcn_rcpf(den.x), __builtin_amdgcn_rcpf(den.y)};
        A = vfma2(num, inv, A);
    };

    // ---- prologue: rows 0..9, no emission, no LDS ----
#pragma unroll 1
    for (int r = 0; r < 10; r += 2) {
        float xA = xp[0],  aA0 = fp0[0],  aA1 = fp1[0],  aA2 = fp2[0];
        float xB = xp[HW], aB0 = fp0[HW], aB1 = fp1[HW], aB2 = fp2[HW];
        xp += 2 * HW; fp0 += 2 * HW; fp1 += 2 * HW; fp2 += 2 * HW;
        vstep(xA, aA0, aA1, aA2, false);
        vstep(xB, aB0, aB1, aB2, false);
    }
    // xp/fp* now point at main input row 0 (tile output row 0 completes here)

    const int n_pair = n_out >> 1;   // 11

    // preload pair 0 (rows 0,1 relative)
    float xA = xp[0],  aA0 = fp0[0],  aA1 = fp1[0],  aA2 = fp2[0];
    float xB = xp[HW], aB0 = fp0[HW], aB1 = fp1[HW], aB2 = fp2[HW];

    // ---- main loop: 2 emit rows per iteration, prefetch next pair ----
#pragma unroll 1
    for (int p = 0; p < n_pair; ++p) {
        // prefetch next pair's stream rows (clamped; for odd n_out the last
        // prefetch leaves the tail row in xA/aA*)
        const int rb = 2 * (p + 1);
        const int r1 = (rb     < n_out) ? rb     : (n_out - 1);
        const int r2 = (rb + 1 < n_out) ? rb + 1 : (n_out - 1);
        const int o1 = r1 * HW, o2 = r2 * HW;
        const float nxA = xp[o1], naA0 = fp0[o1], naA1 = fp1[o1], naA2 = fp2[o1];
        const float nxB = xp[o2], naB0 = fp0[o2], naB1 = fp1[o2], naB2 = fp2[o2];

        v2f mf0, mf1, mf2, cc0, cc1, cc2;
        if (act) {   // moments for this thread's h-row (row 2p+half)
            mf0 = *(const v2f*)(mp);
            mf1 = *(const v2f*)(mp + NPIX);
            mf2 = *(const v2f*)(mp + 2 * NPIX);
            cc0 = *(const v2f*)(cp);
            cc1 = *(const v2f*)(cp + NPIX);
            cc2 = *(const v2f*)(cp + 2 * NPIX);
            mp += 2 * OW; cp += 2 * OW;
        }

        const int e = 2 * p;
        const int sA = e & 3, sB = (e + 1) & 3;
        vstep(xA, aA0, aA1, aA2, true);
        eb[sA][0][t] = eE01.x; eb[sA][1][t] = eE01.y;
        eb[sA][2][t] = eE23.x; eb[sA][3][t] = eE23.y;
        eb[sA][4][t] = eE4;
        vstep(xB, aB0, aB1, aB2, true);
        eb[sB][0][t] = eE01.x; eb[sB][1][t] = eE01.y;
        eb[sB][2][t] = eE23.x; eb[sB][3][t] = eE23.y;
        eb[sB][4][t] = eE4;
        __syncthreads();

        xA = nxA; aA0 = naA0; aA1 = naA1; aA2 = naA2;
        xB = nxB; aB0 = naB0; aB1 = naB1; aB2 = naB2;

        if (act) {
            const int sH = half ? sB : sA;
            v2f hacc[5];
#pragma unroll
            for (int f = 0; f < 5; ++f) {
                const float* ep = &eb[sH][f][cu];
                v2f a = {0.f, 0.f};
#pragma unroll
                for (int m = 0; m < 6; ++m) {
                    v2f rd = *(const v2f*)(ep + 2 * m);
                    a = vfma2(WA[m], __builtin_shufflevector(rd, rd, 0, 0), a);
                    a = vfma2(WB[m], __builtin_shufflevector(rd, rd, 1, 1), a);
                }
                hacc[f] = a;
            }
            const v2f mux  = hacc[0];
            const v2f sigc = hacc[1] - mux * mux;
            ssim2(mux, sigc, mf0, cc0, hacc[2], A0);
            ssim2(mux, sigc, mf1, cc1, hacc[3], A1);
            ssim2(mux, sigc, mf2, cc2, hacc[4], A2);
        }
    }

    // ---- odd tail row (n_out = 23 tiles): data already in xA/aA* ----
    if (n_out & 1) {
        const int e = n_out - 1;
        vstep(xA, aA0, aA1, aA2, true);
        const int sA = e & 3;
        eb[sA][0][t] = eE01.x; eb[sA][1][t] = eE01.y;
        eb[sA][2][t] = eE23.x; eb[sA][3][t] = eE23.y;
        eb[sA][4][t] = eE4;
        __syncthreads();
        if (act && half == 0) {
            v2f mf0 = *(const v2f*)(mp);
            v2f mf1 = *(const v2f*)(mp + NPIX);
            v2f mf2 = *(const v2f*)(mp + 2 * NPIX);
            v2f cc0 = *(const v2f*)(cp);
            v2f cc1 = *(const v2f*)(cp + NPIX);
            v2f cc2 = *(const v2f*)(cp + 2 * NPIX);
            v2f hacc[5];
#pragma unroll
            for (int f = 0; f < 5; ++f) {
                const float* ep = &eb[sA][f][cu];
                v2f a = {0.f, 0.f};
#pragma unroll
                for (int m = 0; m < 6; ++m) {
                    v2f rd = *(const v2f*)(ep + 2 * m);
                    a = vfma2(WA[m], __builtin_shufflevector(rd, rd, 0, 0), a);
                    a = vfma2(WB[m], __builtin_shufflevector(rd, rd, 1, 1), a);
                }
                hacc[f] = a;
            }
            const v2f mux  = hacc[0];
            const v2f sigc = hacc[1] - mux * mux;
            ssim2(mux, sigc, mf0, cc0, hacc[2], A0);
            ssim2(mux, sigc, mf1, cc1, hacc[3], A1);
            ssim2(mux, sigc, mf2, cc2, hacc[4], A2);
        }
    }

    // ---- block reduction (3 waves) ----
    float acc0 = A0.x + A0.y;
    float acc1 = A1.x + A1.y;
    float acc2 = A2.x + A2.y;
#pragma unroll
    for (int off = 32; off > 0; off >>= 1) {
        acc0 += __shfl_down(acc0, off);
        acc1 += __shfl_down(acc1, off);
        acc2 += __shfl_down(acc2, off);
    }
    const int wid = t >> 6, lane = t & 63;
    if (lane == 0) { red[0][wid] = acc0; red[1][wid] = acc1; red[2][wid] = acc2; }
    __syncthreads();
    if (t == 0) {
        const size_t o = (size_t)tile * 1536 + (size_t)b * 192;
        part[o +   0 + c] = red[0][0] + red[0][1] + red[0][2];
        part[o +  64 + c] = red[1][0] + red[1][1] + red[1][2];
        part[o + 128 + c] = red[2][0] + red[2][1] + red[2][2];
    }
}

// ---------------------------------------------------------------------------
// Kernel 3: combine tile partials -> ssim_info, then conv gate + MLP + sigmoid
// ---------------------------------------------------------------------------
__global__ __launch_bounds__(64) void gate_kernel(const float* __restrict__ part,
                                                  const float* __restrict__ sw,
                                                  const float* __restrict__ W1,
                                                  const float* __restrict__ b1,
                                                  const float* __restrict__ W2,
                                                  const float* __restrict__ b2,
                                                  float* __restrict__ out,
                                                  float* __restrict__ out_ssim) {
    const int b = blockIdx.x;
    const int c = threadIdx.x;   // 0..63

    __shared__ float s[3][64];
    __shared__ float h0[64];
    __shared__ float h1[64];

    const float inv = 1.f / (float)NPIX;
#pragma unroll
    for (int f = 0; f < 3; ++f) {
        const int i = b * 192 + f * 64 + c;
        float v = 0.f;
#pragma unroll
        for (int k = 0; k < NTILE; ++k) v += part[i + k * 1536];
        v *= inv;
        s[f][c] = v;
        out_ssim[i] = v;
    }
    __syncthreads();

    float a = 0.f;
#pragma unroll
    for (int f = 0; f < 3; ++f)
#pragma unroll
        for (int i = 0; i < 3; ++i) {
            int cc = c - 1 + i;
            if (cc >= 0 && cc < 64) a += sw[f * 3 + i] * s[f][cc];
        }
    h0[c] = fmaxf(a, 0.f);
    __syncthreads();

    float a1 = b1[c];
    for (int j = 0; j < 64; ++j) a1 += W1[c * 64 + j] * h0[j];
    h1[c] = fmaxf(a1, 0.f);
    __syncthreads();

    float a2 = b2[c];
    for (int j = 0; j < 64; ++j) a2 += W2[c * 64 + j] * h1[j];
    out[b * 64 + c] = 1.f / (1.f + expf(-a2));
}

// ---------------------------------------------------------------------------
extern "C" void kernel_launch(void* const* d_in, const int* in_sizes, int n_in,
                              void* d_out, int out_size, void* d_ws, size_t ws_size,
                              hipStream_t stream) {
    const float* x  = (const float*)d_in[0];
    const float* xf = (const float*)d_in[1];
    const float* sw = (const float*)d_in[2];
    const float* W1 = (const float*)d_in[3];
    const float* b1 = (const float*)d_in[4];
    const float* W2 = (const float*)d_in[5];
    const float* b2 = (const float*)d_in[6];
    float* out = (float*)d_out;

    float* muf  = (float*)d_ws;            // [24][182*182]
    float* sigf = muf + 24 * NPIX;         // [24][182*182]  (sig + C2)
    float* part = sigf + 24 * NPIX;        // [NTILE][8][3][64]

    muf_kernel <<<24 * 14,        256, 0, stream>>>(xf, muf, sigf);
    ssim_kernel<<<8 * 64 * NTILE, 192, 0, stream>>>(x, xf, muf, sigf, part);
    gate_kernel<<<8,               64, 0, stream>>>(part, sw, W1, b1, W2, b2, out, out + 512);
}